// Round 1
// baseline (626.087 us; speedup 1.0000x reference)
//
#include <hip/hip_runtime.h>
#include <hip/hip_bf16.h>

#define M_TOKENS 4096
#define K_IN     4096
#define N_OUT    11008
#define GROUPSIZE 128

#define BM 128
#define BN 128
#define BK 64

typedef __bf16 bf16x8 __attribute__((ext_vector_type(8)));
typedef float  f32x4  __attribute__((ext_vector_type(4)));

__device__ __forceinline__ void async_copy16(const void* g, void* l) {
    __builtin_amdgcn_global_load_lds(
        (const __attribute__((address_space(1))) void*)g,
        (__attribute__((address_space(3))) void*)l,
        16, 0, 0);
}

// ---- x fp32 -> bf16 cast, 8 elems/thread ----
__global__ __launch_bounds__(256) void cast_x_kernel(const float* __restrict__ x,
                                                     __hip_bfloat16* __restrict__ xb) {
    size_t idx = (size_t)blockIdx.x * 256 + threadIdx.x;   // one per 8 elements
    const float4* xf = reinterpret_cast<const float4*>(x) + idx * 2;
    float4 a = xf[0], b = xf[1];
    float v[8] = {a.x, a.y, a.z, a.w, b.x, b.y, b.z, b.w};
    alignas(16) __hip_bfloat16 t[8];
#pragma unroll
    for (int j = 0; j < 8; ++j) t[j] = __float2bfloat16(v[j]);
    *reinterpret_cast<uint4*>(xb + idx * 8) = *reinterpret_cast<const uint4*>(t);
}

// ---- int4-code dequant: wq[n,k] int32 -> wb[n,k] bf16 (B^T layout), 8 k/thread ----
__global__ __launch_bounds__(256) void dequant_kernel(const int* __restrict__ wq,
                                                      const float* __restrict__ snz,
                                                      __hip_bfloat16* __restrict__ wb) {
    size_t idx = (size_t)blockIdx.x * 256 + threadIdx.x;   // n*(K/8) + k8
    int n  = (int)(idx >> 9);         // K_IN/8 = 512
    int k8 = (int)(idx & 511);
    int g  = k8 >> 4;                 // (k8*8)/128
    const float* sz = snz + ((size_t)g * N_OUT + n) * 2;
    float scale = sz[0], zero = sz[1];
    const int4* q4 = reinterpret_cast<const int4*>(wq + (size_t)n * K_IN + (size_t)k8 * 8);
    int4 qa = q4[0], qb = q4[1];
    int q[8] = {qa.x, qa.y, qa.z, qa.w, qb.x, qb.y, qb.z, qb.w};
    alignas(16) __hip_bfloat16 t[8];
#pragma unroll
    for (int j = 0; j < 8; ++j)
        t[j] = __float2bfloat16((float)(q[j] - 8) * scale + zero);
    *reinterpret_cast<uint4*>(wb + idx * 8) = *reinterpret_cast<const uint4*>(t);
}

// ---- bf16 GEMM, C = Xb[M,K] @ Wb[N,K]^T, fp32 out. m97-structure 128x128 tile. ----
__global__ __launch_bounds__(256) void gemm_bt_kernel(const __hip_bfloat16* __restrict__ Xb,
                                                      const __hip_bfloat16* __restrict__ Wb,
                                                      float* __restrict__ C) {
    __shared__ __hip_bfloat16 Alds[BM * BK];   // [128][64] linear
    __shared__ __hip_bfloat16 Blds[BN * BK];   // [128][64] linear

    const int tid  = threadIdx.x;
    const int lane = tid & 63;
    const int wave = tid >> 6;

    // XCD-bijective swizzle (grid = 2752, divisible by 8)
    unsigned nwg = gridDim.x;
    unsigned bid = blockIdx.x;
    unsigned per = nwg >> 3;
    unsigned swz = (bid & 7u) * per + (bid >> 3);
    const int tn = (int)(swz % (N_OUT / BN));   // 86 n-tiles
    const int tm = (int)(swz / (N_OUT / BN));   // 32 m-tiles
    const int m0 = tm * BM;
    const int n0 = tn * BN;

    const int wr = wave >> 1;   // 2x2 wave grid, each wave does 64x64
    const int wc = wave & 1;

    f32x4 acc[4][4];
#pragma unroll
    for (int i = 0; i < 4; ++i)
#pragma unroll
        for (int j = 0; j < 4; ++j) {
            f32x4 z = {0.f, 0.f, 0.f, 0.f};
            acc[i][j] = z;
        }

    const int lrow8 = lane >> 3;          // 0..7
    const int lcol  = (lane & 7) << 3;    // 0,8,...,56  (bf16 elems)

    for (int k0 = 0; k0 < K_IN; k0 += BK) {
        __syncthreads();   // previous tile's reads done before overwrite
        // stage A and B tiles: 4 chunks/wave each, 1024B per issue
#pragma unroll
        for (int i = 0; i < 4; ++i) {
            int chunk = wave * 4 + i;          // 0..15, 8 rows each
            int row = chunk * 8 + lrow8;
            const __hip_bfloat16* gA = Xb + (size_t)(m0 + row) * K_IN + k0 + lcol;
            async_copy16(gA, &Alds[chunk * 512]);
            const __hip_bfloat16* gB = Wb + (size_t)(n0 + row) * K_IN + k0 + lcol;
            async_copy16(gB, &Blds[chunk * 512]);
        }
        __syncthreads();   // vmcnt(0) drain -> tile visible

#pragma unroll
        for (int ks = 0; ks < 2; ++ks) {
            bf16x8 a[4], b[4];
            const int kbase = ks * 32 + ((lane >> 4) << 3);
#pragma unroll
            for (int mi = 0; mi < 4; ++mi)
                a[mi] = *reinterpret_cast<const bf16x8*>(
                    &Alds[(wr * 64 + mi * 16 + (lane & 15)) * BK + kbase]);
#pragma unroll
            for (int ni = 0; ni < 4; ++ni)
                b[ni] = *reinterpret_cast<const bf16x8*>(
                    &Blds[(wc * 64 + ni * 16 + (lane & 15)) * BK + kbase]);
#pragma unroll
            for (int mi = 0; mi < 4; ++mi)
#pragma unroll
                for (int ni = 0; ni < 4; ++ni)
                    acc[mi][ni] = __builtin_amdgcn_mfma_f32_16x16x32_bf16(
                        a[mi], b[ni], acc[mi][ni], 0, 0, 0);
        }
    }

    // epilogue: D lane layout col=lane&15, row=(lane>>4)*4+i
    const int rbase = (lane >> 4) << 2;
    const int cbase = lane & 15;
#pragma unroll
    for (int mi = 0; mi < 4; ++mi)
#pragma unroll
        for (int ni = 0; ni < 4; ++ni)
#pragma unroll
            for (int i = 0; i < 4; ++i) {
                int row = m0 + wr * 64 + mi * 16 + rbase + i;
                int col = n0 + wc * 64 + ni * 16 + cbase;
                C[(size_t)row * N_OUT + col] = acc[mi][ni][i];
            }
}

extern "C" void kernel_launch(void* const* d_in, const int* in_sizes, int n_in,
                              void* d_out, int out_size, void* d_ws, size_t ws_size,
                              hipStream_t stream) {
    const float* x   = (const float*)d_in[0];
    const int*   wq  = (const int*)d_in[1];
    const float* snz = (const float*)d_in[2];
    float* out = (float*)d_out;

    __hip_bfloat16* Xb = (__hip_bfloat16*)d_ws;                               // 32 MB
    __hip_bfloat16* Wb = (__hip_bfloat16*)((char*)d_ws + (size_t)M_TOKENS * K_IN * 2); // 86 MB

    // x cast: M*K/8 = 2097152 threads = 8192 blocks exactly
    cast_x_kernel<<<(M_TOKENS * (size_t)K_IN) / 8 / 256, 256, 0, stream>>>(x, Xb);
    // dequant: N*K/8 = 5636096 threads = 22016 blocks exactly
    dequant_kernel<<<((size_t)N_OUT * K_IN) / 8 / 256, 256, 0, stream>>>(wq, snz, Wb);
    // GEMM: (4096/128)*(11008/128) = 32*86 = 2752 blocks
    gemm_bt_kernel<<<(M_TOKENS / BM) * (N_OUT / BN), 256, 0, stream>>>(Xb, Wb, out);
}

// Round 2
// 388.603 us; speedup vs baseline: 1.6111x; 1.6111x over previous
//
#include <hip/hip_runtime.h>
#include <hip/hip_bf16.h>

#define M_TOKENS 4096
#define K_IN     4096
#define N_OUT    11008

#define BM 256
#define BN 256
#define BK 64
#define KTILES (K_IN / BK)   // 64

typedef __bf16 bf16x8 __attribute__((ext_vector_type(8)));
typedef float  f32x4  __attribute__((ext_vector_type(4)));

__device__ __forceinline__ void async_copy16(const void* g, void* l) {
    __builtin_amdgcn_global_load_lds(
        (const __attribute__((address_space(1))) void*)g,
        (__attribute__((address_space(3))) void*)l, 16, 0, 0);
}

// ---- x fp32 -> bf16 cast, 8 elems/thread ----
__global__ __launch_bounds__(256) void cast_x_kernel(const float* __restrict__ x,
                                                     __hip_bfloat16* __restrict__ xb) {
    size_t idx = (size_t)blockIdx.x * 256 + threadIdx.x;
    const float4* xf = reinterpret_cast<const float4*>(x) + idx * 2;
    float4 a = xf[0], b = xf[1];
    float v[8] = {a.x, a.y, a.z, a.w, b.x, b.y, b.z, b.w};
    alignas(16) __hip_bfloat16 t[8];
#pragma unroll
    for (int j = 0; j < 8; ++j) t[j] = __float2bfloat16(v[j]);
    *reinterpret_cast<uint4*>(xb + idx * 8) = *reinterpret_cast<const uint4*>(t);
}

// ---- int4-code dequant: wq[n,k] int32 -> wb[n,k] bf16 (B^T layout), 8 k/thread ----
__global__ __launch_bounds__(256) void dequant_kernel(const int* __restrict__ wq,
                                                      const float* __restrict__ snz,
                                                      __hip_bfloat16* __restrict__ wb) {
    size_t idx = (size_t)blockIdx.x * 256 + threadIdx.x;   // n*(K/8) + k8
    int n  = (int)(idx >> 9);         // K_IN/8 = 512
    int k8 = (int)(idx & 511);
    int g  = k8 >> 4;                 // (k8*8)/128
    const float* sz = snz + ((size_t)g * N_OUT + n) * 2;
    float scale = sz[0], zero = sz[1];
    const int4* q4 = reinterpret_cast<const int4*>(wq + (size_t)n * K_IN + (size_t)k8 * 8);
    int4 qa = q4[0], qb = q4[1];
    int q[8] = {qa.x, qa.y, qa.z, qa.w, qb.x, qb.y, qb.z, qb.w};
    alignas(16) __hip_bfloat16 t[8];
#pragma unroll
    for (int j = 0; j < 8; ++j)
        t[j] = __float2bfloat16((float)(q[j] - 8) * scale + zero);
    *reinterpret_cast<uint4*>(wb + idx * 8) = *reinterpret_cast<const uint4*>(t);
}

// ================= 256x256 8-phase bf16 GEMM (m201-style template) =================
// C[M,N] = Xb[M,K] @ Wb[N,K]^T, fp32 out. 8 waves (2M x 4N), BK=64, 2 K-tiles/iter.
// LDS: 2 dbuf x (A 32KB + B 32KB) = 128KB. Swizzle: slot ^= (row&7), 16B slots,
// applied via pre-swizzled GLOBAL source (linear global_load_lds dest) + swizzled read.

#define SBAR() { __builtin_amdgcn_sched_barrier(0); __builtin_amdgcn_s_barrier(); __builtin_amdgcn_sched_barrier(0); }
#define LGKM0() { asm volatile("s_waitcnt lgkmcnt(0)" ::: "memory"); __builtin_amdgcn_sched_barrier(0); }
#define VM6()  { asm volatile("s_waitcnt vmcnt(6)" ::: "memory"); }

#define QUAD(AOFF, B, NOFF) \
    __builtin_amdgcn_s_setprio(1); \
    { \
        _Pragma("unroll") for (int kk = 0; kk < 2; ++kk) \
        _Pragma("unroll") for (int mi = 0; mi < 4; ++mi) \
        _Pragma("unroll") for (int ni = 0; ni < 2; ++ni) \
            acc[AOFF + mi][NOFF + ni] = __builtin_amdgcn_mfma_f32_16x16x32_bf16( \
                a[mi][kk], B[ni][kk], acc[AOFF + mi][NOFF + ni], 0, 0, 0); \
    } \
    __builtin_amdgcn_s_setprio(0);

#define RD_A(TILE, QA) \
    _Pragma("unroll") for (int mi = 0; mi < 4; ++mi) \
    _Pragma("unroll") for (int kk = 0; kk < 2; ++kk) \
        a[mi][kk] = readA(TILE, (QA) * 4 + mi, kk);

#define RD_B(TILE, DST, QB) \
    _Pragma("unroll") for (int ni = 0; ni < 2; ++ni) \
    _Pragma("unroll") for (int kk = 0; kk < 2; ++kk) \
        DST[ni][kk] = readB(TILE, (QB) * 2 + ni, kk);

__global__ __launch_bounds__(512, 2) void gemm8p_kernel(
        const __hip_bfloat16* __restrict__ Xb,
        const __hip_bfloat16* __restrict__ Wb,
        float* __restrict__ C) {
    __shared__ alignas(16) char smem[131072];
    char* const ldsA = smem;            // [2][256 rows][64 bf16 = 128B]
    char* const ldsB = smem + 65536;

    const int tid  = threadIdx.x;
    const int lane = tid & 63;
    const int wave = tid >> 6;
    const int wr   = wave >> 2;     // 0..1  (M half)
    const int wc   = wave & 3;      // 0..3  (N quarter)
    const int l15  = lane & 15;
    const int lrow = lane >> 3;     // staging row-in-chunk
    const int ssw  = (((lane & 7) ^ lrow) << 4);   // pre-swizzled source col (bytes)

    // XCD-bijective swizzle (grid = 688, 688 % 8 == 0)
    unsigned bid = blockIdx.x;
    unsigned per = gridDim.x >> 3;               // 86
    unsigned swz = (bid & 7u) * per + (bid >> 3);
    const int tn = (int)(swz % (N_OUT / BN));    // 43
    const int tm = (int)(swz / (N_OUT / BN));    // 16
    const int m0 = tm * BM;
    const int n0 = tn * BN;

    // swizzled read column (bytes within a 128B row); kk toggles bit 6
    const int colswz = (((lane >> 4) << 4) ^ ((lane & 7) << 4));

    f32x4 acc[8][4];
#pragma unroll
    for (int i = 0; i < 8; ++i)
#pragma unroll
        for (int j = 0; j < 4; ++j) {
            f32x4 z = {0.f, 0.f, 0.f, 0.f};
            acc[i][j] = z;
        }
    bf16x8 a[4][2], b0[2][2], b1[2][2];

    // stage one 16KB half-tile unit (2 x global_load_lds/thread, 1KB/wave-issue)
    auto stageA = [&](char* dstTile, int kt, int unit) {
#pragma unroll
        for (int j = 0; j < 2; ++j) {
            int c  = wave * 2 + j;
            int rb = (c >> 3) * 128 + (c & 7) * 8 + unit * 64;   // unit0: rows 0-63,128-191
            const char* g = (const char*)Xb + ((size_t)(m0 + rb + lrow) * K_IN) * 2
                            + (size_t)kt * 128 + ssw;
            async_copy16(g, dstTile + rb * 128);
        }
    };
    auto stageB = [&](char* dstTile, int kt, int unit) {
#pragma unroll
        for (int j = 0; j < 2; ++j) {
            int c  = wave * 2 + j;
            int rb = (c >> 2) * 64 + (c & 3) * 8 + unit * 32;    // unit0: rows 0-31,64-95,...
            const char* g = (const char*)Wb + ((size_t)(n0 + rb + lrow) * K_IN) * 2
                            + (size_t)kt * 128 + ssw;
            async_copy16(g, dstTile + rb * 128);
        }
    };
    auto readA = [&](char* tile, int mi8, int kk) -> bf16x8 {
        return *(const bf16x8*)(tile + (wr * 128 + mi8 * 16 + l15) * 128 + (colswz ^ (kk << 6)));
    };
    auto readB = [&](char* tile, int ni4, int kk) -> bf16x8 {
        return *(const bf16x8*)(tile + (wc * 64 + ni4 * 16 + l15) * 128 + (colswz ^ (kk << 6)));
    };

    char* const A0 = ldsA;           char* const A1 = ldsA + 32768;
    char* const Bt0 = ldsB;          char* const Bt1 = ldsB + 32768;

    // ---- prologue: buf0 <- kt0 (4 units), buf1 <- kt1 (3 units; A_u1 comes at ph1) ----
    stageA(A0, 0, 0); stageB(Bt0, 0, 0); stageB(Bt0, 0, 1); stageA(A0, 0, 1);
    stageA(A1, 1, 0); stageB(Bt1, 1, 0); stageB(Bt1, 1, 1);
    VM6(); SBAR();

    for (int i = 0; i < KTILES / 2; ++i) {
        const int kt1 = 2 * i + 1;
        const int kt2 = (2 * i + 2) & (KTILES - 1);   // wraps harmlessly on last iter
        const int kt3 = (2 * i + 3) & (KTILES - 1);

        // ---- phase 1: Q(0,0) on buf0; stage buf1 A_u1 (kt1, just-in-time) ----
        RD_A(A0, 0); RD_B(Bt0, b0, 0);
        stageA(A1, kt1, 1);
        SBAR(); LGKM0();
        QUAD(0, b0, 0);
        SBAR();

        // ---- phase 2: Q(0,1); stage buf0 A_u0 (kt2) ----
        RD_B(Bt0, b1, 1);
        stageA(A0, kt2, 0);
        SBAR(); LGKM0();
        QUAD(0, b1, 2);
        SBAR();

        // ---- phase 3: Q(1,1); stage buf0 B_u0 (kt2) ----
        RD_A(A0, 1);
        stageB(Bt0, kt2, 0);
        SBAR(); LGKM0();
        QUAD(4, b1, 2);
        SBAR();

        // ---- phase 4: Q(1,0); stage buf0 B_u1 (kt2); counted drain ----
        stageB(Bt0, kt2, 1);
        SBAR(); LGKM0();
        QUAD(4, b0, 0);
        VM6(); SBAR();

        // ---- phase 5: Q(0,0) on buf1; stage buf0 A_u1 (kt2) ----
        RD_A(A1, 0); RD_B(Bt1, b0, 0);
        stageA(A0, kt2, 1);
        SBAR(); LGKM0();
        QUAD(0, b0, 0);
        SBAR();

        // ---- phase 6: Q(0,1); stage buf1 A_u0 (kt3) ----
        RD_B(Bt1, b1, 1);
        stageA(A1, kt3, 0);
        SBAR(); LGKM0();
        QUAD(0, b1, 2);
        SBAR();

        // ---- phase 7: Q(1,1); stage buf1 B_u0 (kt3) ----
        RD_A(A1, 1);
        stageB(Bt1, kt3, 0);
        SBAR(); LGKM0();
        QUAD(4, b1, 2);
        SBAR();

        // ---- phase 8: Q(1,0); stage buf1 B_u1 (kt3); counted drain ----
        stageB(Bt1, kt3, 1);
        SBAR(); LGKM0();
        QUAD(4, b0, 0);
        VM6(); SBAR();
    }

    // ---- epilogue: D layout col=lane&15, row=(lane>>4)*4+e ----
    const int r4 = (lane >> 4) << 2;
#pragma unroll
    for (int mi = 0; mi < 8; ++mi)
#pragma unroll
        for (int ni = 0; ni < 4; ++ni)
#pragma unroll
            for (int e = 0; e < 4; ++e) {
                int row = m0 + wr * 128 + mi * 16 + r4 + e;
                int col = n0 + wc * 64 + ni * 16 + l15;
                C[(size_t)row * N_OUT + col] = acc[mi][ni][e];
            }
}

extern "C" void kernel_launch(void* const* d_in, const int* in_sizes, int n_in,
                              void* d_out, int out_size, void* d_ws, size_t ws_size,
                              hipStream_t stream) {
    const float* x   = (const float*)d_in[0];
    const int*   wq  = (const int*)d_in[1];
    const float* snz = (const float*)d_in[2];
    float* out = (float*)d_out;

    __hip_bfloat16* Xb = (__hip_bfloat16*)d_ws;                                        // 32 MB
    __hip_bfloat16* Wb = (__hip_bfloat16*)((char*)d_ws + (size_t)M_TOKENS * K_IN * 2); // 86 MB

    cast_x_kernel<<<(M_TOKENS * (size_t)K_IN) / 8 / 256, 256, 0, stream>>>(x, Xb);
    dequant_kernel<<<((size_t)N_OUT * K_IN) / 8 / 256, 256, 0, stream>>>(wq, snz, Wb);
    gemm8p_kernel<<<(M_TOKENS / BM) * (N_OUT / BN), 512, 0, stream>>>(Xb, Wb, out);
}

// Round 4
// 387.629 us; speedup vs baseline: 1.6152x; 1.0025x over previous
//
#include <hip/hip_runtime.h>
#include <hip/hip_bf16.h>

#define M_TOKENS 4096
#define K_IN     4096
#define N_OUT    11008

#define BM 256
#define BN 256
#define BK 64
#define KTILES (K_IN / BK)   // 64

typedef __bf16 bf16x8 __attribute__((ext_vector_type(8)));
typedef float  f32x4  __attribute__((ext_vector_type(4)));

__device__ __forceinline__ void async_copy16(const void* g, void* l) {
    __builtin_amdgcn_global_load_lds(
        (const __attribute__((address_space(1))) void*)g,
        (__attribute__((address_space(3))) void*)l, 16, 0, 0);
}

// ---- x fp32 -> bf16 cast, 8 elems/thread ----
__global__ __launch_bounds__(256) void cast_x_kernel(const float* __restrict__ x,
                                                     __hip_bfloat16* __restrict__ xb) {
    size_t idx = (size_t)blockIdx.x * 256 + threadIdx.x;
    const float4* xf = reinterpret_cast<const float4*>(x) + idx * 2;
    float4 a = xf[0], b = xf[1];
    float v[8] = {a.x, a.y, a.z, a.w, b.x, b.y, b.z, b.w};
    alignas(16) __hip_bfloat16 t[8];
#pragma unroll
    for (int j = 0; j < 8; ++j) t[j] = __float2bfloat16(v[j]);
    *reinterpret_cast<uint4*>(xb + idx * 8) = *reinterpret_cast<const uint4*>(t);
}

// ---- int4-code dequant: wq[n,k] int32 -> wb[n,k] bf16 (B^T layout), 8 k/thread ----
__global__ __launch_bounds__(256) void dequant_kernel(const int* __restrict__ wq,
                                                      const float* __restrict__ snz,
                                                      __hip_bfloat16* __restrict__ wb) {
    size_t idx = (size_t)blockIdx.x * 256 + threadIdx.x;   // n*(K/8) + k8
    int n  = (int)(idx >> 9);         // K_IN/8 = 512
    int k8 = (int)(idx & 511);
    int g  = k8 >> 4;                 // (k8*8)/128
    const float* sz = snz + ((size_t)g * N_OUT + n) * 2;
    float scale = sz[0], zero = sz[1];
    const int4* q4 = reinterpret_cast<const int4*>(wq + (size_t)n * K_IN + (size_t)k8 * 8);
    int4 qa = q4[0], qb = q4[1];
    int q[8] = {qa.x, qa.y, qa.z, qa.w, qb.x, qb.y, qb.z, qb.w};
    alignas(16) __hip_bfloat16 t[8];
#pragma unroll
    for (int j = 0; j < 8; ++j)
        t[j] = __float2bfloat16((float)(q[j] - 8) * scale + zero);
    *reinterpret_cast<uint4*>(wb + idx * 8) = *reinterpret_cast<const uint4*>(t);
}

// ================= 256x256 bf16 GEMM, kk-balanced 4-phase/K-tile schedule ==========
// C[M,N] = Xb[M,K] @ Wb[N,K]^T, fp32 out. 8 waves (2M x 4N), BK=64.
// Phases per K-tile: {aL+b kk0 | 16 MFMA}, {aH kk0 | 16}, {aL+b kk1 | 16}, {aH kk1 | 16}
// -> ds_read_b128 per wave per phase = {8,4,8,4}.
// CORRECTNESS INVARIANT (round-3 lesson): vmcnt drains are per-wave, and waves read
// LDS rows staged by OTHER waves' global_load_lds. So every counted drain must be
// WAIT-THEN-BARRIER: vmcnt(N) *before* an s_barrier, with consuming ds_reads issued
// only after that barrier. Drains at end-of-phA and end-of-phD (+prologue) cover
// exactly the units the next phase reads (ledger-verified).

#define SCB()  __builtin_amdgcn_sched_barrier(0)
#define SBAR() { SCB(); __builtin_amdgcn_s_barrier(); SCB(); }
#define LGKM0() { asm volatile("s_waitcnt lgkmcnt(0)" ::: "memory"); SCB(); }
#define VM4()  { asm volatile("s_waitcnt vmcnt(4)" ::: "memory"); SCB(); }

#define RD_AL(T, KK) \
    _Pragma("unroll") for (int mi = 0; mi < 4; ++mi) aL[mi] = readA(T, mi, KK);
#define RD_AH(T, KK) \
    _Pragma("unroll") for (int mi = 0; mi < 4; ++mi) aH[mi] = readA(T, 4 + mi, KK);
#define RD_B4(T, KK) \
    _Pragma("unroll") for (int ni = 0; ni < 4; ++ni) bk[ni] = readB(T, ni, KK);

#define MFMA16(AOFF, FRAG) \
    __builtin_amdgcn_s_setprio(1); \
    { \
        _Pragma("unroll") for (int mi = 0; mi < 4; ++mi) \
        _Pragma("unroll") for (int ni = 0; ni < 4; ++ni) \
            acc[AOFF + mi][ni] = __builtin_amdgcn_mfma_f32_16x16x32_bf16( \
                FRAG[mi], bk[ni], acc[AOFF + mi][ni], 0, 0, 0); \
    } \
    __builtin_amdgcn_s_setprio(0);

// One K-tile: consume (CA,CB); stage next-tile units into (NA,NB); K1 = kt+1, K2 = kt+2.
#define TILE(CA, CB, NA, NB, K1, K2) \
    /* phA: reads CAu0+CB kk0 (guaranteed by previous end-of-phD drain) */ \
    RD_AL(CA, 0); RD_B4(CB, 0); \
    stageB(NB, K1, 1); \
    SBAR(); LGKM0(); \
    MFMA16(0, aL); \
    VM4(); SBAR();   /* drains CAu1 for phB */ \
    /* phB */ \
    RD_AH(CA, 0); \
    stageA(NA, K1, 0); \
    SBAR(); LGKM0(); \
    MFMA16(4, aH); \
    SBAR(); \
    /* phC: re-reads kk1 of already-guaranteed data */ \
    RD_AL(CA, 1); RD_B4(CB, 1); \
    stageA(NA, K1, 1); \
    SBAR(); LGKM0(); \
    MFMA16(0, aL); \
    SBAR(); \
    /* phD */ \
    RD_AH(CA, 1); \
    stageB(CB, K2, 0); \
    SBAR(); LGKM0(); \
    MFMA16(4, aH); \
    VM4(); SBAR();   /* drains NAu0, NBu0, NBu1 for next tile's phA */

__global__ __launch_bounds__(512, 2) void gemm8p_kernel(
        const __hip_bfloat16* __restrict__ Xb,
        const __hip_bfloat16* __restrict__ Wb,
        float* __restrict__ C) {
    __shared__ alignas(16) char smem[131072];
    char* const ldsA = smem;            // [2][256 rows][64 bf16 = 128B]
    char* const ldsB = smem + 65536;

    const int tid  = threadIdx.x;
    const int lane = tid & 63;
    const int wave = tid >> 6;
    const int wr   = wave >> 2;     // 0..1  (M half)
    const int wc   = wave & 3;      // 0..3  (N quarter)
    const int l15  = lane & 15;
    const int lrow = lane >> 3;     // staging row-in-chunk
    const int ssw  = (((lane & 7) ^ lrow) << 4);   // pre-swizzled source col (bytes)

    // XCD-bijective swizzle (grid = 688, 688 % 8 == 0)
    unsigned bid = blockIdx.x;
    unsigned per = gridDim.x >> 3;               // 86
    unsigned swz = (bid & 7u) * per + (bid >> 3);
    const int tn = (int)(swz % (N_OUT / BN));    // 43
    const int tm = (int)(swz / (N_OUT / BN));    // 16
    const int m0 = tm * BM;
    const int n0 = tn * BN;

    // swizzled read column (bytes within a 128B row); kk toggles bit 6
    const int colswz = (((lane >> 4) << 4) ^ ((lane & 7) << 4));

    f32x4 acc[8][4];
#pragma unroll
    for (int i = 0; i < 8; ++i)
#pragma unroll
        for (int j = 0; j < 4; ++j) {
            f32x4 z = {0.f, 0.f, 0.f, 0.f};
            acc[i][j] = z;
        }
    bf16x8 aL[4], aH[4], bk[4];

    // stage one 16KB unit (2 x global_load_lds/thread, 1KB/wave-issue)
    auto stageA = [&](char* dstTile, int kt, int unit) {
#pragma unroll
        for (int j = 0; j < 2; ++j) {
            int c  = wave * 2 + j;
            int rb = (c >> 3) * 128 + (c & 7) * 8 + unit * 64;   // u0: rows 0-63,128-191
            const char* g = (const char*)Xb + ((size_t)(m0 + rb + lrow) * K_IN) * 2
                            + (size_t)kt * 128 + ssw;
            async_copy16(g, dstTile + rb * 128);
        }
    };
    auto stageB = [&](char* dstTile, int kt, int unit) {
#pragma unroll
        for (int j = 0; j < 2; ++j) {
            int c  = wave * 2 + j;
            int rb = (c >> 2) * 64 + (c & 3) * 8 + unit * 32;    // u0: rows 0-31 of each 64-seg
            const char* g = (const char*)Wb + ((size_t)(n0 + rb + lrow) * K_IN) * 2
                            + (size_t)kt * 128 + ssw;
            async_copy16(g, dstTile + rb * 128);
        }
    };
    auto readA = [&](char* tile, int mi8, int kk) -> bf16x8 {
        return *(const bf16x8*)(tile + (wr * 128 + mi8 * 16 + l15) * 128 + (colswz ^ (kk << 6)));
    };
    auto readB = [&](char* tile, int ni4, int kk) -> bf16x8 {
        return *(const bf16x8*)(tile + (wc * 64 + ni4 * 16 + l15) * 128 + (colswz ^ (kk << 6)));
    };

    char* const A0 = ldsA;   char* const A1 = ldsA + 32768;
    char* const B0 = ldsB;   char* const B1 = ldsB + 32768;

    // ---- prologue: [B0u0, B0u1, A0u0, A0u1, B1u0]; drain first 3 units, then barrier ----
    stageB(B0, 0, 0); stageB(B0, 0, 1); stageA(A0, 0, 0); stageA(A0, 0, 1);
    stageB(B1, 1, 0);
    VM4(); SBAR();

    for (int i = 0; i < KTILES / 2; ++i) {
        const int k1 = (2 * i + 1) & (KTILES - 1);
        const int k2 = (2 * i + 2) & (KTILES - 1);
        const int k3 = (2 * i + 3) & (KTILES - 1);
        TILE(A0, B0, A1, B1, k1, k2)   // tile 2i   (buf0)
        TILE(A1, B1, A0, B0, k2, k3)   // tile 2i+1 (buf1)
    }

    // ---- epilogue: D layout col=lane&15, row=(lane>>4)*4+e ----
    const int r4 = (lane >> 4) << 2;
#pragma unroll
    for (int mi = 0; mi < 8; ++mi)
#pragma unroll
        for (int ni = 0; ni < 4; ++ni)
#pragma unroll
            for (int e = 0; e < 4; ++e) {
                int row = m0 + wr * 128 + mi * 16 + r4 + e;
                int col = n0 + wc * 64 + ni * 16 + l15;
                C[(size_t)row * N_OUT + col] = acc[mi][ni][e];
            }
}

extern "C" void kernel_launch(void* const* d_in, const int* in_sizes, int n_in,
                              void* d_out, int out_size, void* d_ws, size_t ws_size,
                              hipStream_t stream) {
    const float* x   = (const float*)d_in[0];
    const int*   wq  = (const int*)d_in[1];
    const float* snz = (const float*)d_in[2];
    float* out = (float*)d_out;

    __hip_bfloat16* Xb = (__hip_bfloat16*)d_ws;                                        // 32 MB
    __hip_bfloat16* Wb = (__hip_bfloat16*)((char*)d_ws + (size_t)M_TOKENS * K_IN * 2); // 86 MB

    cast_x_kernel<<<(M_TOKENS * (size_t)K_IN) / 8 / 256, 256, 0, stream>>>(x, Xb);
    dequant_kernel<<<((size_t)N_OUT * K_IN) / 8 / 256, 256, 0, stream>>>(wq, snz, Wb);
    gemm8p_kernel<<<(M_TOKENS / BM) * (N_OUT / BN), 512, 0, stream>>>(Xb, Wb, out);
}